// Round 1
// baseline (1641.496 us; speedup 1.0000x reference)
//
#include <hip/hip_runtime.h>
#include <hip/hip_bf16.h>
#include <math.h>

// Problem constants (FusionDTI)
#define BATCH 32
#define LP 2048
#define LDRUG 512
#define DP 1280
#define DD 768
#define GP 256      // LP/8
#define GD 64       // LDRUG/8
#define HID 512
#define NH 8
#define HD 64

// ---------------------------------------------------------------------------
// Group mean: out[row, d] = mean_j in[row*8+j, d]   (row = b*G+g works because
// L == 8*G exactly, so flat row indexing matches the per-batch grouping)
// ---------------------------------------------------------------------------
__global__ void group_mean_kernel(const float* __restrict__ in,
                                  float* __restrict__ out, int D, int total) {
    int o = blockIdx.x * blockDim.x + threadIdx.x;
    if (o >= total) return;
    int d = o % D;
    long row = o / D;
    const float* p = in + (row * 8) * (long)D + d;
    float s = 0.f;
#pragma unroll
    for (int j = 0; j < 8; ++j) s += p[(long)j * D];
    out[o] = s * 0.125f;
}

__global__ void group_mask_kernel(const int* __restrict__ m,
                                  int* __restrict__ out, int total) {
    int o = blockIdx.x * blockDim.x + threadIdx.x;
    if (o >= total) return;
    const int* p = m + (long)o * 8;
    int any = 0;
#pragma unroll
    for (int j = 0; j < 8; ++j) any |= p[j];
    out[o] = any ? 1 : 0;
}

// ---------------------------------------------------------------------------
// Tiled fp32 GEMM: C[M,N] = A[M,K] @ W[K,N] (+ bias). All dims divisible by
// tile sizes for this problem (M in {8192,2048}, K in {1280,768,512}, N=512).
// ---------------------------------------------------------------------------
template<int TBM, int TBN, int TM, int TN>
__global__ __launch_bounds__(256) void gemm_kernel(const float* __restrict__ A,
        const float* __restrict__ W, const float* __restrict__ bias,
        float* __restrict__ C, int M, int K, int N) {
    constexpr int BK = 16;
    __shared__ float As[BK][TBM];   // As[k][m] (transposed for stride-1 m)
    __shared__ float Bs[BK][TBN];   // Bs[k][n]
    const int t = threadIdx.x;
    const int m0 = blockIdx.y * TBM, n0 = blockIdx.x * TBN;
    constexpr int AF4 = TBM * BK / (256 * 4);
    constexpr int BF4 = TBN * BK / (256 * 4);
    const int txn = t % (TBN / TN);
    const int tym = t / (TBN / TN);
    float acc[TM][TN] = {};
    for (int k0 = 0; k0 < K; k0 += BK) {
#pragma unroll
        for (int it = 0; it < AF4; ++it) {
            int f4 = t + it * 256;
            int row = f4 >> 2;            // 4 float4 per row of 16 k
            int kc = (f4 & 3) << 2;
            float4 v = *(const float4*)(A + (size_t)(m0 + row) * K + k0 + kc);
            As[kc + 0][row] = v.x; As[kc + 1][row] = v.y;
            As[kc + 2][row] = v.z; As[kc + 3][row] = v.w;
        }
#pragma unroll
        for (int it = 0; it < BF4; ++it) {
            int f4 = t + it * 256;
            int krow = f4 / (TBN / 4);
            int nc = (f4 % (TBN / 4)) << 2;
            float4 v = *(const float4*)(W + (size_t)(k0 + krow) * N + n0 + nc);
            *(float4*)&Bs[krow][nc] = v;
        }
        __syncthreads();
#pragma unroll
        for (int kk = 0; kk < BK; ++kk) {
            float a[TM], b[TN];
#pragma unroll
            for (int i = 0; i < TM; i += 4)
                *(float4*)&a[i] = *(const float4*)&As[kk][tym * TM + i];
#pragma unroll
            for (int j = 0; j < TN; j += 4)
                *(float4*)&b[j] = *(const float4*)&Bs[kk][txn * TN + j];
#pragma unroll
            for (int i = 0; i < TM; ++i)
#pragma unroll
                for (int j = 0; j < TN; ++j)
                    acc[i][j] += a[i] * b[j];
        }
        __syncthreads();
    }
#pragma unroll
    for (int i = 0; i < TM; ++i) {
        int m = m0 + tym * TM + i;
        float* crow = C + (size_t)m * N + n0 + txn * TN;
#pragma unroll
        for (int j = 0; j < TN; ++j) {
            float v = acc[i][j];
            if (bias) v += bias[n0 + txn * TN + j];
            crow[j] = v;
        }
    }
}

// ---------------------------------------------------------------------------
// Fused cross-attention block: one block = 8 query rows of one (b, head).
// Computes logits vs ALL prot keys (256) and ALL drug keys (64), applies the
// reference's (logit - 1e6) pair-masking, two separate softmaxes, mixes with
// vp/vd, scales 0.5, zeroes invalid query rows. Never materializes alphas in
// global memory.
// ---------------------------------------------------------------------------
__global__ __launch_bounds__(256) void attn_kernel(
        const float* __restrict__ q, const int* __restrict__ rowmask, int G_rows,
        const float* __restrict__ kp, const float* __restrict__ vp, const int* __restrict__ cmaskp,
        const float* __restrict__ kd, const float* __restrict__ vd, const int* __restrict__ cmaskd,
        float* __restrict__ out) {
    __shared__ float sQ[8][64];
    __shared__ float sLp[8][GP];
    __shared__ float sLd[8][GD];
    __shared__ int sMrow[8];
    const int t = threadIdx.x;
    const int i0 = blockIdx.x * 8;
    const int h = blockIdx.y;
    const int b = blockIdx.z;

    // phase 1: load 8 q rows + row masks
    {
        int idx = t;
#pragma unroll
        for (int rep = 0; rep < 2; ++rep, idx += 256) {
            int r = idx >> 6, d = idx & 63;
            sQ[r][d] = q[(size_t)(b * G_rows + i0 + r) * HID + h * HD + d];
        }
        if (t < 8) sMrow[t] = rowmask[b * G_rows + i0 + t];
    }
    __syncthreads();

    // phase 2: prot-key logits, one key per thread (k = t, 256 keys)
    {
        const int k = t;
        const float4* kr = (const float4*)(kp + (size_t)(b * GP + k) * HID + h * HD);
        float dot[8] = {0, 0, 0, 0, 0, 0, 0, 0};
#pragma unroll
        for (int d4 = 0; d4 < 16; ++d4) {
            float4 kv = kr[d4];
#pragma unroll
            for (int r = 0; r < 8; ++r) {
                float4 qv = *(const float4*)&sQ[r][d4 * 4];
                dot[r] += qv.x * kv.x + qv.y * kv.y + qv.z * kv.z + qv.w * kv.w;
            }
        }
        int cm = cmaskp[b * GP + k];
#pragma unroll
        for (int r = 0; r < 8; ++r)
            sLp[r][k] = dot[r] - ((sMrow[r] && cm) ? 0.f : 1e6f);
    }
    // phase 3: drug-key logits (64 keys x 8 rows, thread covers 2 rows)
    {
        const int kdi = t & 63, rb = t >> 6;
        const int r0 = rb * 2, r1 = r0 + 1;
        const float4* kr = (const float4*)(kd + (size_t)(b * GD + kdi) * HID + h * HD);
        float d0 = 0.f, d1 = 0.f;
#pragma unroll
        for (int d4 = 0; d4 < 16; ++d4) {
            float4 kv = kr[d4];
            float4 q0 = *(const float4*)&sQ[r0][d4 * 4];
            float4 q1 = *(const float4*)&sQ[r1][d4 * 4];
            d0 += q0.x * kv.x + q0.y * kv.y + q0.z * kv.z + q0.w * kv.w;
            d1 += q1.x * kv.x + q1.y * kv.y + q1.z * kv.z + q1.w * kv.w;
        }
        int cm = cmaskd[b * GD + kdi];
        sLd[r0][kdi] = d0 - ((sMrow[r0] && cm) ? 0.f : 1e6f);
        sLd[r1][kdi] = d1 - ((sMrow[r1] && cm) ? 0.f : 1e6f);
    }
    __syncthreads();

    // phase 4: two independent softmaxes per row; wave w owns rows {w, w+4}
    {
        const int lane = t & 63, w = t >> 6;
#pragma unroll
        for (int rr = 0; rr < 2; ++rr) {
            const int r = w + rr * 4;
            // prot softmax over 256
            float x0 = sLp[r][lane], x1 = sLp[r][lane + 64];
            float x2 = sLp[r][lane + 128], x3 = sLp[r][lane + 192];
            float m = fmaxf(fmaxf(x0, x1), fmaxf(x2, x3));
#pragma unroll
            for (int off = 32; off >= 1; off >>= 1) m = fmaxf(m, __shfl_xor(m, off));
            float e0 = __expf(x0 - m), e1 = __expf(x1 - m);
            float e2 = __expf(x2 - m), e3 = __expf(x3 - m);
            float s = e0 + e1 + e2 + e3;
#pragma unroll
            for (int off = 32; off >= 1; off >>= 1) s += __shfl_xor(s, off);
            float inv = 1.f / s;
            sLp[r][lane] = e0 * inv; sLp[r][lane + 64] = e1 * inv;
            sLp[r][lane + 128] = e2 * inv; sLp[r][lane + 192] = e3 * inv;
            // drug softmax over 64
            float y = sLd[r][lane];
            float m2 = y;
#pragma unroll
            for (int off = 32; off >= 1; off >>= 1) m2 = fmaxf(m2, __shfl_xor(m2, off));
            float e = __expf(y - m2);
            float s2 = e;
#pragma unroll
            for (int off = 32; off >= 1; off >>= 1) s2 += __shfl_xor(s2, off);
            sLd[r][lane] = e / s2;
        }
    }
    __syncthreads();

    // phase 5: mix with v; wave w owns rows {w, w+4}; lane = output dim d
    {
        const int d = t & 63, w = t >> 6;
        const int r0 = w, r1 = w + 4;
        float a0 = 0.f, a1 = 0.f;
        const float* vpp = vp + (size_t)b * GP * HID + h * HD + d;
#pragma unroll 4
        for (int k4 = 0; k4 < GP / 4; ++k4) {
            float4 c0 = *(const float4*)&sLp[r0][k4 * 4];
            float4 c1 = *(const float4*)&sLp[r1][k4 * 4];
            float v0 = vpp[(size_t)(k4 * 4 + 0) * HID];
            float v1 = vpp[(size_t)(k4 * 4 + 1) * HID];
            float v2 = vpp[(size_t)(k4 * 4 + 2) * HID];
            float v3 = vpp[(size_t)(k4 * 4 + 3) * HID];
            a0 += c0.x * v0 + c0.y * v1 + c0.z * v2 + c0.w * v3;
            a1 += c1.x * v0 + c1.y * v1 + c1.z * v2 + c1.w * v3;
        }
        const float* vdp = vd + (size_t)b * GD * HID + h * HD + d;
#pragma unroll 4
        for (int k4 = 0; k4 < GD / 4; ++k4) {
            float4 c0 = *(const float4*)&sLd[r0][k4 * 4];
            float4 c1 = *(const float4*)&sLd[r1][k4 * 4];
            float v0 = vdp[(size_t)(k4 * 4 + 0) * HID];
            float v1 = vdp[(size_t)(k4 * 4 + 1) * HID];
            float v2 = vdp[(size_t)(k4 * 4 + 2) * HID];
            float v3 = vdp[(size_t)(k4 * 4 + 3) * HID];
            a0 += c0.x * v0 + c0.y * v1 + c0.z * v2 + c0.w * v3;
            a1 += c1.x * v0 + c1.y * v1 + c1.z * v2 + c1.w * v3;
        }
        size_t o0 = (size_t)(b * G_rows + i0 + r0) * HID + h * HD + d;
        size_t o1 = (size_t)(b * G_rows + i0 + r1) * HID + h * HD + d;
        out[o0] = sMrow[r0] ? 0.5f * a0 : 0.f;
        out[o1] = sMrow[r1] ? 0.5f * a1 : 0.f;
    }
}

// ---------------------------------------------------------------------------
// Masked-mean pool + concat -> x[B,1024]
// ---------------------------------------------------------------------------
__global__ void pool_kernel(const float* __restrict__ pe, const float* __restrict__ de,
                            const int* __restrict__ mg, const int* __restrict__ md,
                            float* __restrict__ x) {
    const int b = blockIdx.x, d = threadIdx.x;   // 512 threads
    float cnt = 0.f;
    for (int i = 0; i < GP; ++i) cnt += mg[b * GP + i] ? 1.f : 0.f;
    float s = 0.f;
    const float* p = pe + (size_t)b * GP * HID + d;
    for (int i = 0; i < GP; ++i) s += p[(size_t)i * HID];
    x[b * 1024 + d] = s / cnt;
    float cntd = 0.f;
    for (int i = 0; i < GD; ++i) cntd += md[b * GD + i] ? 1.f : 0.f;
    float sd = 0.f;
    const float* pd = de + (size_t)b * GD * HID + d;
    for (int i = 0; i < GD; ++i) sd += pd[(size_t)i * HID];
    x[b * 1024 + 512 + d] = sd / cntd;
}

// ---------------------------------------------------------------------------
// Tiny-M (32) MLP GEMM: one thread per output element, W reads coalesced.
// ---------------------------------------------------------------------------
__global__ void mlp_gemm_kernel(const float* __restrict__ X, const float* __restrict__ W,
                                const float* __restrict__ bias, float* __restrict__ Y,
                                int K, int N, int do_relu) {
    int g = blockIdx.x * blockDim.x + threadIdx.x;
    int m = g / N, n = g % N;
    float acc = bias[n];
    const float* xr = X + (size_t)m * K;
    const float* wc = W + n;
#pragma unroll 4
    for (int k = 0; k < K; ++k) acc += xr[k] * wc[(size_t)k * N];
    if (do_relu) acc = fmaxf(acc, 0.f);
    Y[g] = acc;
}

// Training-mode BatchNorm1d over batch of 32, biased variance, in place.
__global__ void bn_kernel(float* __restrict__ Y, const float* __restrict__ gamma,
                          const float* __restrict__ beta, int F) {
    int f = blockIdx.x * blockDim.x + threadIdx.x;
    if (f >= F) return;
    float mu = 0.f;
    for (int r = 0; r < BATCH; ++r) mu += Y[(size_t)r * F + f];
    mu *= (1.f / BATCH);
    float var = 0.f;
    for (int r = 0; r < BATCH; ++r) {
        float d = Y[(size_t)r * F + f] - mu;
        var += d * d;
    }
    var *= (1.f / BATCH);
    float sc = gamma[f] * rsqrtf(var + 1e-5f);
    float bb = beta[f];
    for (int r = 0; r < BATCH; ++r)
        Y[(size_t)r * F + f] = (Y[(size_t)r * F + f] - mu) * sc + bb;
}

__global__ void final_kernel(const float* __restrict__ H, const float* __restrict__ wo,
                             const float* __restrict__ bo, float* __restrict__ out) {
    const int b = blockIdx.x, lane = threadIdx.x;   // 64 threads
    float p = 0.f;
#pragma unroll
    for (int j = 0; j < 4; ++j) {
        int idx = lane + j * 64;
        p += H[b * 256 + idx] * wo[idx];
    }
#pragma unroll
    for (int off = 32; off >= 1; off >>= 1) p += __shfl_xor(p, off);
    if (lane == 0) out[b] = 1.f / (1.f + expf(-(p + bo[0])));
}

// ---------------------------------------------------------------------------
extern "C" void kernel_launch(void* const* d_in, const int* in_sizes, int n_in,
                              void* d_out, int out_size, void* d_ws, size_t ws_size,
                              hipStream_t stream) {
    const float* prot_embed = (const float*)d_in[0];
    const float* drug_embed = (const float*)d_in[1];
    const int* prot_mask = (const int*)d_in[2];
    const int* drug_mask = (const int*)d_in[3];
    const float* w_preg = (const float*)d_in[4];
    const float* b_preg = (const float*)d_in[5];
    const float* w_dreg = (const float*)d_in[6];
    const float* b_dreg = (const float*)d_in[7];
    const float* wqp = (const float*)d_in[8];
    const float* wkp = (const float*)d_in[9];
    const float* wvp = (const float*)d_in[10];
    const float* wqd = (const float*)d_in[11];
    const float* wkd = (const float*)d_in[12];
    const float* wvd = (const float*)d_in[13];
    const float* w1 = (const float*)d_in[14];  const float* b1 = (const float*)d_in[15];
    const float* g1 = (const float*)d_in[16];  const float* be1 = (const float*)d_in[17];
    const float* w2 = (const float*)d_in[18];  const float* b2 = (const float*)d_in[19];
    const float* g2 = (const float*)d_in[20];  const float* be2 = (const float*)d_in[21];
    const float* w3 = (const float*)d_in[22];  const float* b3 = (const float*)d_in[23];
    const float* g3 = (const float*)d_in[24];  const float* be3 = (const float*)d_in[25];
    const float* wo = (const float*)d_in[26];  const float* bo = (const float*)d_in[27];

    // workspace layout (floats). pgm region is reused for pe/de after it dies;
    // dgm region reused for x/h1/h2/h3.
    float* ws = (float*)d_ws;
    float* pgm = ws;                       // 10485760  [32,256,1280]
    float* dgm = pgm + 10485760;           // 1572864   [32,64,768]
    float* pg  = dgm + 1572864;            // 4194304   [32,256,512]
    float* dg  = pg + 4194304;             // 1048576   [32,64,512]
    float* qp  = dg + 1048576;             // 4194304
    float* kp  = qp + 4194304;             // 4194304
    float* vp  = kp + 4194304;             // 4194304
    float* qd  = vp + 4194304;             // 1048576
    float* kd  = qd + 1048576;             // 1048576
    float* vd  = kd + 1048576;             // 1048576
    int*   mg  = (int*)(vd + 1048576);     // 8192 ints
    int*   md  = mg + 8192;                // 2048 ints
    // reuse (lifetimes verified: pgm dead after pg GEMM; dgm dead after dg GEMM)
    float* pe  = pgm;                      // 4194304   [32,256,512]
    float* de  = pgm + 4194304;            // 1048576   [32,64,512]
    float* x   = dgm;                      // 32768     [32,1024]
    float* h1  = x + 32768;                // 32768
    float* h2  = h1 + 32768;               // 16384
    float* h3  = h2 + 16384;               // 8192

    // 1. group means (mean commutes with the linear regression layers)
    group_mean_kernel<<<(BATCH * GP * DP) / 256, 256, 0, stream>>>(prot_embed, pgm, DP, BATCH * GP * DP);
    group_mean_kernel<<<(BATCH * GD * DD) / 256, 256, 0, stream>>>(drug_embed, dgm, DD, BATCH * GD * DD);
    group_mask_kernel<<<(BATCH * GP) / 256, 256, 0, stream>>>(prot_mask, mg, BATCH * GP);
    group_mask_kernel<<<(BATCH * GD) / 256, 256, 0, stream>>>(drug_mask, md, BATCH * GD);

    // 2. regression GEMMs (bias)
    dim3 gbig(HID / 64, (BATCH * GP) / 128);
    dim3 gsml(HID / 64, (BATCH * GD) / 64);
    gemm_kernel<128, 64, 8, 4><<<gbig, 256, 0, stream>>>(pgm, w_preg, b_preg, pg, BATCH * GP, DP, HID);
    gemm_kernel<64, 64, 4, 4><<<gsml, 256, 0, stream>>>(dgm, w_dreg, b_dreg, dg, BATCH * GD, DD, HID);

    // 3. QKV projections (no bias)
    gemm_kernel<128, 64, 8, 4><<<gbig, 256, 0, stream>>>(pg, wqp, nullptr, qp, BATCH * GP, HID, HID);
    gemm_kernel<128, 64, 8, 4><<<gbig, 256, 0, stream>>>(pg, wkp, nullptr, kp, BATCH * GP, HID, HID);
    gemm_kernel<128, 64, 8, 4><<<gbig, 256, 0, stream>>>(pg, wvp, nullptr, vp, BATCH * GP, HID, HID);
    gemm_kernel<64, 64, 4, 4><<<gsml, 256, 0, stream>>>(dg, wqd, nullptr, qd, BATCH * GD, HID, HID);
    gemm_kernel<64, 64, 4, 4><<<gsml, 256, 0, stream>>>(dg, wkd, nullptr, kd, BATCH * GD, HID, HID);
    gemm_kernel<64, 64, 4, 4><<<gsml, 256, 0, stream>>>(dg, wvd, nullptr, vd, BATCH * GD, HID, HID);

    // 4. fused cross-attention (prot queries, then drug queries)
    dim3 gap(GP / 8, NH, BATCH);
    attn_kernel<<<gap, 256, 0, stream>>>(qp, mg, GP, kp, vp, mg, kd, vd, md, pe);
    dim3 gad(GD / 8, NH, BATCH);
    attn_kernel<<<gad, 256, 0, stream>>>(qd, md, GD, kp, vp, mg, kd, vd, md, de);

    // 5. masked-mean pool + concat
    pool_kernel<<<BATCH, 512, 0, stream>>>(pe, de, mg, md, x);

    // 6. MLP head: (GEMM+ReLU) -> BN, x3, then sigmoid output
    mlp_gemm_kernel<<<(BATCH * 1024) / 256, 256, 0, stream>>>(x, w1, b1, h1, 1024, 1024, 1);
    bn_kernel<<<1024 / 256, 256, 0, stream>>>(h1, g1, be1, 1024);
    mlp_gemm_kernel<<<(BATCH * 512) / 256, 256, 0, stream>>>(h1, w2, b2, h2, 1024, 512, 1);
    bn_kernel<<<512 / 256, 256, 0, stream>>>(h2, g2, be2, 512);
    mlp_gemm_kernel<<<(BATCH * 256) / 256, 256, 0, stream>>>(h2, w3, b3, h3, 512, 256, 1);
    bn_kernel<<<1, 256, 0, stream>>>(h3, g3, be3, 256);
    final_kernel<<<BATCH, 64, 0, stream>>>(h3, wo, bo, (float*)d_out);
}

// Round 2
// 1291.956 us; speedup vs baseline: 1.2706x; 1.2706x over previous
//
#include <hip/hip_runtime.h>
#include <hip/hip_bf16.h>
#include <math.h>

// Problem constants (FusionDTI)
#define BATCH 32
#define LP 2048
#define LDRUG 512
#define DP 1280
#define DD 768
#define GP 256      // LP/8
#define GD 64       // LDRUG/8
#define HID 512
#define NH 8
#define HD 64

typedef unsigned short ushort_t;
typedef __attribute__((ext_vector_type(8))) __bf16 bf16x8;
typedef __attribute__((ext_vector_type(4))) float f32x4;

__device__ __forceinline__ ushort_t f2bf(float f) {
    unsigned int u = __float_as_uint(f);
    u += 0x7fff + ((u >> 16) & 1);          // round-to-nearest-even
    return (ushort_t)(u >> 16);
}

// ---------------------------------------------------------------------------
// Group mean -> bf16: out[row, d] = mean_j in[row*8+j, d]
// ---------------------------------------------------------------------------
__global__ void group_mean_kernel(const float* __restrict__ in,
                                  ushort_t* __restrict__ out, int D, int total) {
    int o = blockIdx.x * blockDim.x + threadIdx.x;
    if (o >= total) return;
    int d = o % D;
    long row = o / D;
    const float* p = in + (row * 8) * (long)D + d;
    float s = 0.f;
#pragma unroll
    for (int j = 0; j < 8; ++j) s += p[(long)j * D];
    out[o] = f2bf(s * 0.125f);
}

__global__ void group_mask_kernel(const int* __restrict__ m,
                                  int* __restrict__ out, int total) {
    int o = blockIdx.x * blockDim.x + threadIdx.x;
    if (o >= total) return;
    const int* p = m + (long)o * 8;
    int any = 0;
#pragma unroll
    for (int j = 0; j < 8; ++j) any |= p[j];
    out[o] = any ? 1 : 0;
}

// ---------------------------------------------------------------------------
// Transpose + cast: Wt[n][k] = bf16(W[k][n]).  K,N multiples of 32.
// ---------------------------------------------------------------------------
__global__ __launch_bounds__(256) void transpose_cast_kernel(
        const float* __restrict__ W, ushort_t* __restrict__ Wt, int K, int N) {
    __shared__ float tile[32][33];
    int k0 = blockIdx.x * 32, n0 = blockIdx.y * 32;
    int tx = threadIdx.x & 31, ty = threadIdx.x >> 5;   // ty 0..7
#pragma unroll
    for (int i = 0; i < 32; i += 8)
        tile[ty + i][tx] = W[(size_t)(k0 + ty + i) * N + n0 + tx];
    __syncthreads();
#pragma unroll
    for (int i = 0; i < 32; i += 8)
        Wt[(size_t)(n0 + ty + i) * K + k0 + tx] = f2bf(tile[tx][ty + i]);
}

// ---------------------------------------------------------------------------
// MFMA bf16 GEMM (m97 structure): C[M,N] = A[M,K] @ Bt[N,K]^T (+bias)
// 128x128 tile, BK=32, 256 threads (4 waves in 2x2), 16x16x32 bf16 MFMA.
// A, Bt bf16 row-major; C fp32 or bf16.
// ---------------------------------------------------------------------------
template<bool OUT_BF16, bool BIAS>
__global__ __launch_bounds__(256) void mfma_gemm_kernel(
        const ushort_t* __restrict__ A, const ushort_t* __restrict__ Bt,
        const float* __restrict__ bias, void* __restrict__ Cv,
        int M, int N, int K) {
    __shared__ ushort_t As[128 * 32];   // [m][k] 8 KB
    __shared__ ushort_t Bs[128 * 32];   // [n][k] 8 KB
    const int t = threadIdx.x;
    const int m0 = blockIdx.y * 128, n0 = blockIdx.x * 128;
    const int wavebase = (t >> 6) * 64;          // wave-uniform chunk base
    const int lane = t & 63;
    const int lrow = lane & 15, quad = lane >> 4;
    const int m_base = ((t >> 6) >> 1) * 64;     // wave row (0/64)
    const int n_base = ((t >> 6) & 1) * 64;      // wave col (0/64)
    f32x4 acc[4][4] = {};

    for (int k0 = 0; k0 < K; k0 += 32) {
#pragma unroll
        for (int it = 0; it < 2; ++it) {
            int c = it * 256 + t;                // 16B chunk id, 512 total
            int row = c >> 2, kc = (c & 3) * 8;  // 4 chunks per 32-k row
            __builtin_amdgcn_global_load_lds(
                (const __attribute__((address_space(1))) void*)(A + (size_t)(m0 + row) * K + k0 + kc),
                (__attribute__((address_space(3))) void*)(As + (size_t)(it * 256 + wavebase) * 8),
                16, 0, 0);
            __builtin_amdgcn_global_load_lds(
                (const __attribute__((address_space(1))) void*)(Bt + (size_t)(n0 + row) * K + k0 + kc),
                (__attribute__((address_space(3))) void*)(Bs + (size_t)(it * 256 + wavebase) * 8),
                16, 0, 0);
        }
        __syncthreads();
        bf16x8 af[4], bfr[4];
#pragma unroll
        for (int i = 0; i < 4; ++i)
            af[i] = *(const bf16x8*)(As + (m_base + i * 16 + lrow) * 32 + quad * 8);
#pragma unroll
        for (int j = 0; j < 4; ++j)
            bfr[j] = *(const bf16x8*)(Bs + (n_base + j * 16 + lrow) * 32 + quad * 8);
#pragma unroll
        for (int i = 0; i < 4; ++i)
#pragma unroll
            for (int j = 0; j < 4; ++j)
                acc[i][j] = __builtin_amdgcn_mfma_f32_16x16x32_bf16(af[i], bfr[j], acc[i][j], 0, 0, 0);
        __syncthreads();
    }
    // epilogue: C/D layout col=lane&15, row=quad*4+reg (m89/m91 verified)
#pragma unroll
    for (int i = 0; i < 4; ++i) {
#pragma unroll
        for (int j = 0; j < 4; ++j) {
            int n = n0 + n_base + j * 16 + lrow;
            float bv = BIAS ? bias[n] : 0.f;
#pragma unroll
            for (int r = 0; r < 4; ++r) {
                int m = m0 + m_base + i * 16 + quad * 4 + r;
                float v = acc[i][j][r] + bv;
                if (OUT_BF16) ((ushort_t*)Cv)[(size_t)m * N + n] = f2bf(v);
                else          ((float*)Cv)[(size_t)m * N + n] = v;
            }
        }
    }
}

// ---------------------------------------------------------------------------
// Fused cross-attention block (fp32): one block = 8 query rows of one (b,head).
// q/k/v row strides parameterized (fused QKV buffers use ld=1536).
// ---------------------------------------------------------------------------
__global__ __launch_bounds__(256) void attn_kernel(
        const float* __restrict__ q, int ldq, const int* __restrict__ rowmask, int G_rows,
        const float* __restrict__ kp, const float* __restrict__ vp, int ldp, const int* __restrict__ cmaskp,
        const float* __restrict__ kd, const float* __restrict__ vd, int ldd, const int* __restrict__ cmaskd,
        float* __restrict__ out) {
    __shared__ float sQ[8][64];
    __shared__ float sLp[8][GP];
    __shared__ float sLd[8][GD];
    __shared__ int sMrow[8];
    const int t = threadIdx.x;
    const int i0 = blockIdx.x * 8;
    const int h = blockIdx.y;
    const int b = blockIdx.z;

    {
        int idx = t;
#pragma unroll
        for (int rep = 0; rep < 2; ++rep, idx += 256) {
            int r = idx >> 6, d = idx & 63;
            sQ[r][d] = q[(size_t)(b * G_rows + i0 + r) * ldq + h * HD + d];
        }
        if (t < 8) sMrow[t] = rowmask[b * G_rows + i0 + t];
    }
    __syncthreads();

    // prot-key logits: one key per thread (256 keys)
    {
        const int k = t;
        const float4* kr = (const float4*)(kp + (size_t)(b * GP + k) * ldp + h * HD);
        float dot[8] = {0, 0, 0, 0, 0, 0, 0, 0};
#pragma unroll
        for (int d4 = 0; d4 < 16; ++d4) {
            float4 kv = kr[d4];
#pragma unroll
            for (int r = 0; r < 8; ++r) {
                float4 qv = *(const float4*)&sQ[r][d4 * 4];
                dot[r] += qv.x * kv.x + qv.y * kv.y + qv.z * kv.z + qv.w * kv.w;
            }
        }
        int cm = cmaskp[b * GP + k];
#pragma unroll
        for (int r = 0; r < 8; ++r)
            sLp[r][k] = dot[r] - ((sMrow[r] && cm) ? 0.f : 1e6f);
    }
    // drug-key logits (64 keys x 8 rows; thread covers 2 rows)
    {
        const int kdi = t & 63, rb = t >> 6;
        const int r0 = rb * 2, r1 = r0 + 1;
        const float4* kr = (const float4*)(kd + (size_t)(b * GD + kdi) * ldd + h * HD);
        float d0 = 0.f, d1 = 0.f;
#pragma unroll
        for (int d4 = 0; d4 < 16; ++d4) {
            float4 kv = kr[d4];
            float4 q0 = *(const float4*)&sQ[r0][d4 * 4];
            float4 q1 = *(const float4*)&sQ[r1][d4 * 4];
            d0 += q0.x * kv.x + q0.y * kv.y + q0.z * kv.z + q0.w * kv.w;
            d1 += q1.x * kv.x + q1.y * kv.y + q1.z * kv.z + q1.w * kv.w;
        }
        int cm = cmaskd[b * GD + kdi];
        sLd[r0][kdi] = d0 - ((sMrow[r0] && cm) ? 0.f : 1e6f);
        sLd[r1][kdi] = d1 - ((sMrow[r1] && cm) ? 0.f : 1e6f);
    }
    __syncthreads();

    // softmaxes; wave w owns rows {w, w+4}
    {
        const int lane = t & 63, w = t >> 6;
#pragma unroll
        for (int rr = 0; rr < 2; ++rr) {
            const int r = w + rr * 4;
            float x0 = sLp[r][lane], x1 = sLp[r][lane + 64];
            float x2 = sLp[r][lane + 128], x3 = sLp[r][lane + 192];
            float m = fmaxf(fmaxf(x0, x1), fmaxf(x2, x3));
#pragma unroll
            for (int off = 32; off >= 1; off >>= 1) m = fmaxf(m, __shfl_xor(m, off));
            float e0 = __expf(x0 - m), e1 = __expf(x1 - m);
            float e2 = __expf(x2 - m), e3 = __expf(x3 - m);
            float s = e0 + e1 + e2 + e3;
#pragma unroll
            for (int off = 32; off >= 1; off >>= 1) s += __shfl_xor(s, off);
            float inv = 1.f / s;
            sLp[r][lane] = e0 * inv; sLp[r][lane + 64] = e1 * inv;
            sLp[r][lane + 128] = e2 * inv; sLp[r][lane + 192] = e3 * inv;
            float y = sLd[r][lane];
            float m2 = y;
#pragma unroll
            for (int off = 32; off >= 1; off >>= 1) m2 = fmaxf(m2, __shfl_xor(m2, off));
            float e = __expf(y - m2);
            float s2 = e;
#pragma unroll
            for (int off = 32; off >= 1; off >>= 1) s2 += __shfl_xor(s2, off);
            sLd[r][lane] = e / s2;
        }
    }
    __syncthreads();

    // mix with v; wave w owns rows {w, w+4}; lane = output dim d
    {
        const int d = t & 63, w = t >> 6;
        const int r0 = w, r1 = w + 4;
        float a0 = 0.f, a1 = 0.f;
        const float* vpp = vp + (size_t)b * GP * ldp + h * HD + d;
#pragma unroll 4
        for (int k4 = 0; k4 < GP / 4; ++k4) {
            float4 c0 = *(const float4*)&sLp[r0][k4 * 4];
            float4 c1 = *(const float4*)&sLp[r1][k4 * 4];
            float v0 = vpp[(size_t)(k4 * 4 + 0) * ldp];
            float v1 = vpp[(size_t)(k4 * 4 + 1) * ldp];
            float v2 = vpp[(size_t)(k4 * 4 + 2) * ldp];
            float v3 = vpp[(size_t)(k4 * 4 + 3) * ldp];
            a0 += c0.x * v0 + c0.y * v1 + c0.z * v2 + c0.w * v3;
            a1 += c1.x * v0 + c1.y * v1 + c1.z * v2 + c1.w * v3;
        }
        const float* vdp = vd + (size_t)b * GD * ldd + h * HD + d;
#pragma unroll 4
        for (int k4 = 0; k4 < GD / 4; ++k4) {
            float4 c0 = *(const float4*)&sLd[r0][k4 * 4];
            float4 c1 = *(const float4*)&sLd[r1][k4 * 4];
            float v0 = vdp[(size_t)(k4 * 4 + 0) * ldd];
            float v1 = vdp[(size_t)(k4 * 4 + 1) * ldd];
            float v2 = vdp[(size_t)(k4 * 4 + 2) * ldd];
            float v3 = vdp[(size_t)(k4 * 4 + 3) * ldd];
            a0 += c0.x * v0 + c0.y * v1 + c0.z * v2 + c0.w * v3;
            a1 += c1.x * v0 + c1.y * v1 + c1.z * v2 + c1.w * v3;
        }
        size_t o0 = (size_t)(b * G_rows + i0 + r0) * HID + h * HD + d;
        size_t o1 = (size_t)(b * G_rows + i0 + r1) * HID + h * HD + d;
        out[o0] = sMrow[r0] ? 0.5f * a0 : 0.f;
        out[o1] = sMrow[r1] ? 0.5f * a1 : 0.f;
    }
}

// ---------------------------------------------------------------------------
// Masked-mean pool + concat -> x[B,1024]
// ---------------------------------------------------------------------------
__global__ void pool_kernel(const float* __restrict__ pe, const float* __restrict__ de,
                            const int* __restrict__ mg, const int* __restrict__ md,
                            float* __restrict__ x) {
    const int b = blockIdx.x, d = threadIdx.x;   // 512 threads
    float cnt = 0.f;
    for (int i = 0; i < GP; ++i) cnt += mg[b * GP + i] ? 1.f : 0.f;
    float s = 0.f;
    const float* p = pe + (size_t)b * GP * HID + d;
    for (int i = 0; i < GP; ++i) s += p[(size_t)i * HID];
    x[b * 1024 + d] = s / cnt;
    float cntd = 0.f;
    for (int i = 0; i < GD; ++i) cntd += md[b * GD + i] ? 1.f : 0.f;
    float sd = 0.f;
    const float* pd = de + (size_t)b * GD * HID + d;
    for (int i = 0; i < GD; ++i) sd += pd[(size_t)i * HID];
    x[b * 1024 + 512 + d] = sd / cntd;
}

// ---------------------------------------------------------------------------
// Tiny-M (32) MLP GEMM (fp32), BN, final sigmoid
// ---------------------------------------------------------------------------
__global__ void mlp_gemm_kernel(const float* __restrict__ X, const float* __restrict__ W,
                                const float* __restrict__ bias, float* __restrict__ Y,
                                int K, int N, int do_relu) {
    int g = blockIdx.x * blockDim.x + threadIdx.x;
    int m = g / N, n = g % N;
    float acc = bias[n];
    const float* xr = X + (size_t)m * K;
    const float* wc = W + n;
#pragma unroll 4
    for (int k = 0; k < K; ++k) acc += xr[k] * wc[(size_t)k * N];
    if (do_relu) acc = fmaxf(acc, 0.f);
    Y[g] = acc;
}

__global__ void bn_kernel(float* __restrict__ Y, const float* __restrict__ gamma,
                          const float* __restrict__ beta, int F) {
    int f = blockIdx.x * blockDim.x + threadIdx.x;
    if (f >= F) return;
    float mu = 0.f;
    for (int r = 0; r < BATCH; ++r) mu += Y[(size_t)r * F + f];
    mu *= (1.f / BATCH);
    float var = 0.f;
    for (int r = 0; r < BATCH; ++r) {
        float d = Y[(size_t)r * F + f] - mu;
        var += d * d;
    }
    var *= (1.f / BATCH);
    float sc = gamma[f] * rsqrtf(var + 1e-5f);
    float bb = beta[f];
    for (int r = 0; r < BATCH; ++r)
        Y[(size_t)r * F + f] = (Y[(size_t)r * F + f] - mu) * sc + bb;
}

__global__ void final_kernel(const float* __restrict__ H, const float* __restrict__ wo,
                             const float* __restrict__ bo, float* __restrict__ out) {
    const int b = blockIdx.x, lane = threadIdx.x;   // 64 threads
    float p = 0.f;
#pragma unroll
    for (int j = 0; j < 4; ++j) {
        int idx = lane + j * 64;
        p += H[b * 256 + idx] * wo[idx];
    }
#pragma unroll
    for (int off = 32; off >= 1; off >>= 1) p += __shfl_xor(p, off);
    if (lane == 0) out[b] = 1.f / (1.f + expf(-(p + bo[0])));
}

// ---------------------------------------------------------------------------
extern "C" void kernel_launch(void* const* d_in, const int* in_sizes, int n_in,
                              void* d_out, int out_size, void* d_ws, size_t ws_size,
                              hipStream_t stream) {
    const float* prot_embed = (const float*)d_in[0];
    const float* drug_embed = (const float*)d_in[1];
    const int* prot_mask = (const int*)d_in[2];
    const int* drug_mask = (const int*)d_in[3];
    const float* w_preg = (const float*)d_in[4];
    const float* b_preg = (const float*)d_in[5];
    const float* w_dreg = (const float*)d_in[6];
    const float* b_dreg = (const float*)d_in[7];
    const float* wqp = (const float*)d_in[8];
    const float* wkp = (const float*)d_in[9];
    const float* wvp = (const float*)d_in[10];
    const float* wqd = (const float*)d_in[11];
    const float* wkd = (const float*)d_in[12];
    const float* wvd = (const float*)d_in[13];
    const float* w1 = (const float*)d_in[14];  const float* b1 = (const float*)d_in[15];
    const float* g1 = (const float*)d_in[16];  const float* be1 = (const float*)d_in[17];
    const float* w2 = (const float*)d_in[18];  const float* b2 = (const float*)d_in[19];
    const float* g2 = (const float*)d_in[20];  const float* be2 = (const float*)d_in[21];
    const float* w3 = (const float*)d_in[22];  const float* b3 = (const float*)d_in[23];
    const float* g3 = (const float*)d_in[24];  const float* be3 = (const float*)d_in[25];
    const float* wo = (const float*)d_in[26];  const float* bo = (const float*)d_in[27];

    // workspace layout
    ushort_t* pgm = (ushort_t*)d_ws;                 // [8192][1280] bf16
    ushort_t* dgm = pgm + 10485760;                  // [2048][768] bf16
    ushort_t* wpreg_t = dgm + 1572864;               // [512][1280] bf16
    ushort_t* wdreg_t = wpreg_t + 655360;            // [512][768]
    ushort_t* wqkvp_t = wdreg_t + 393216;            // [1536][512]
    ushort_t* wqkvd_t = wqkvp_t + 786432;            // [1536][512]
    ushort_t* pg = wqkvd_t + 786432;                 // [8192][512] bf16
    ushort_t* dg = pg + 4194304;                     // [2048][512] bf16
    float* qkvp = (float*)(dg + 1048576);            // [8192][1536] fp32
    float* qkvd = qkvp + 12582912;                   // [2048][1536] fp32
    float* pe = qkvd + 3145728;                      // [8192][512]
    float* de = pe + 4194304;                        // [2048][512]
    float* x  = de + 1048576;                        // [32][1024]
    float* h1 = x + 32768;
    float* h2 = h1 + 32768;
    float* h3 = h2 + 16384;
    int* mg = (int*)(h3 + 8192);
    int* md = mg + 8192;

    // 1. group means (mean commutes with the linear regression layers) -> bf16
    group_mean_kernel<<<(BATCH * GP * DP) / 256, 256, 0, stream>>>(prot_embed, pgm, DP, BATCH * GP * DP);
    group_mean_kernel<<<(BATCH * GD * DD) / 256, 256, 0, stream>>>(drug_embed, dgm, DD, BATCH * GD * DD);
    group_mask_kernel<<<(BATCH * GP) / 256, 256, 0, stream>>>(prot_mask, mg, BATCH * GP);
    group_mask_kernel<<<(BATCH * GD) / 256, 256, 0, stream>>>(drug_mask, md, BATCH * GD);

    // 2. weight transpose+cast (QKV concatenated: rows 0-511=q, 512-1023=k, 1024-1535=v)
    transpose_cast_kernel<<<dim3(DP / 32, HID / 32), 256, 0, stream>>>(w_preg, wpreg_t, DP, HID);
    transpose_cast_kernel<<<dim3(DD / 32, HID / 32), 256, 0, stream>>>(w_dreg, wdreg_t, DD, HID);
    transpose_cast_kernel<<<dim3(HID / 32, HID / 32), 256, 0, stream>>>(wqp, wqkvp_t, HID, HID);
    transpose_cast_kernel<<<dim3(HID / 32, HID / 32), 256, 0, stream>>>(wkp, wqkvp_t + 512 * 512, HID, HID);
    transpose_cast_kernel<<<dim3(HID / 32, HID / 32), 256, 0, stream>>>(wvp, wqkvp_t + 1024 * 512, HID, HID);
    transpose_cast_kernel<<<dim3(HID / 32, HID / 32), 256, 0, stream>>>(wqd, wqkvd_t, HID, HID);
    transpose_cast_kernel<<<dim3(HID / 32, HID / 32), 256, 0, stream>>>(wkd, wqkvd_t + 512 * 512, HID, HID);
    transpose_cast_kernel<<<dim3(HID / 32, HID / 32), 256, 0, stream>>>(wvd, wqkvd_t + 1024 * 512, HID, HID);

    // 3. regression GEMMs (bias, bf16 out) then fused QKV GEMMs (fp32 out)
    mfma_gemm_kernel<true, true><<<dim3(HID / 128, (BATCH * GP) / 128), 256, 0, stream>>>(
        pgm, wpreg_t, b_preg, pg, BATCH * GP, HID, DP);
    mfma_gemm_kernel<true, true><<<dim3(HID / 128, (BATCH * GD) / 128), 256, 0, stream>>>(
        dgm, wdreg_t, b_dreg, dg, BATCH * GD, HID, DD);
    mfma_gemm_kernel<false, false><<<dim3(1536 / 128, (BATCH * GP) / 128), 256, 0, stream>>>(
        pg, wqkvp_t, nullptr, qkvp, BATCH * GP, 1536, HID);
    mfma_gemm_kernel<false, false><<<dim3(1536 / 128, (BATCH * GD) / 128), 256, 0, stream>>>(
        dg, wqkvd_t, nullptr, qkvd, BATCH * GD, 1536, HID);

    // 4. fused cross-attention (fp32; q/k/v inside fused buffers, ld=1536)
    const float* qp = qkvp;           const float* kp = qkvp + 512;  const float* vp = qkvp + 1024;
    const float* qd = qkvd;           const float* kd = qkvd + 512;  const float* vd = qkvd + 1024;
    dim3 gap(GP / 8, NH, BATCH);
    attn_kernel<<<gap, 256, 0, stream>>>(qp, 1536, mg, GP, kp, vp, 1536, mg, kd, vd, 1536, md, pe);
    dim3 gad(GD / 8, NH, BATCH);
    attn_kernel<<<gad, 256, 0, stream>>>(qd, 1536, md, GD, kp, vp, 1536, mg, kd, vd, 1536, md, de);

    // 5. masked-mean pool + concat
    pool_kernel<<<BATCH, 512, 0, stream>>>(pe, de, mg, md, x);

    // 6. MLP head
    mlp_gemm_kernel<<<(BATCH * 1024) / 256, 256, 0, stream>>>(x, w1, b1, h1, 1024, 1024, 1);
    bn_kernel<<<1024 / 256, 256, 0, stream>>>(h1, g1, be1, 1024);
    mlp_gemm_kernel<<<(BATCH * 512) / 256, 256, 0, stream>>>(h1, w2, b2, h2, 1024, 512, 1);
    bn_kernel<<<512 / 256, 256, 0, stream>>>(h2, g2, be2, 512);
    mlp_gemm_kernel<<<(BATCH * 256) / 256, 256, 0, stream>>>(h2, w3, b3, h3, 512, 256, 1);
    bn_kernel<<<1, 256, 0, stream>>>(h3, g3, be3, 256);
    final_kernel<<<BATCH, 64, 0, stream>>>(h3, wo, bo, (float*)d_out);
}

// Round 3
// 1032.386 us; speedup vs baseline: 1.5900x; 1.2514x over previous
//
#include <hip/hip_runtime.h>
#include <hip/hip_bf16.h>
#include <math.h>

// Problem constants (FusionDTI)
#define BATCH 32
#define LP 2048
#define LDRUG 512
#define DP 1280
#define DD 768
#define GP 256      // LP/8
#define GD 64       // LDRUG/8
#define HID 512
#define NH 8
#define HD 64
#define NKEY 320    // GP + GD concatenated keys
#define NQ 320      // GP + GD concatenated queries

typedef unsigned short ushort_t;
typedef __attribute__((ext_vector_type(8))) __bf16 bf16x8;
typedef __attribute__((ext_vector_type(8))) _Float16 f16x8;
typedef __attribute__((ext_vector_type(4))) float f32x4;

__device__ __forceinline__ ushort_t f2bf(float f) {
    unsigned int u = __float_as_uint(f);
    u += 0x7fff + ((u >> 16) & 1);          // round-to-nearest-even
    return (ushort_t)(u >> 16);
}

// ---------------------------------------------------------------------------
// Group mean -> bf16, vectorized float4 (4 d per thread)
// ---------------------------------------------------------------------------
__global__ void group_mean_kernel(const float* __restrict__ in,
                                  ushort_t* __restrict__ out, int D4, int total4) {
    int o = blockIdx.x * blockDim.x + threadIdx.x;
    if (o >= total4) return;
    int d = o % D4;
    long row = o / D4;
    const float4* p = (const float4*)in + row * 8 * (long)D4 + d;
    float4 s = {0.f, 0.f, 0.f, 0.f};
#pragma unroll
    for (int j = 0; j < 8; ++j) {
        float4 v = p[(long)j * D4];
        s.x += v.x; s.y += v.y; s.z += v.z; s.w += v.w;
    }
    uint2 r;
    r.x = (unsigned)f2bf(s.x * 0.125f) | ((unsigned)f2bf(s.y * 0.125f) << 16);
    r.y = (unsigned)f2bf(s.z * 0.125f) | ((unsigned)f2bf(s.w * 0.125f) << 16);
    *(uint2*)(out + (size_t)o * 4) = r;
}

__global__ void group_mask_kernel(const int* __restrict__ m,
                                  int* __restrict__ out, int total) {
    int o = blockIdx.x * blockDim.x + threadIdx.x;
    if (o >= total) return;
    const int* p = m + (long)o * 8;
    int any = 0;
#pragma unroll
    for (int j = 0; j < 8; ++j) any |= p[j];
    out[o] = any ? 1 : 0;
}

// ---------------------------------------------------------------------------
// Fused transpose+cast of all 8 weight matrices in ONE launch.
// ---------------------------------------------------------------------------
struct TransJobs {
    const float* src[8];
    ushort_t* dst[8];
    int K[8], N[8], base[8];   // base = first global tile index of job
};
__global__ __launch_bounds__(256) void transpose_cast8_kernel(TransJobs J) {
    __shared__ float tile[32][33];
    int tidx = blockIdx.x;
    int j = 0;
#pragma unroll
    for (int i = 1; i < 8; ++i) if (tidx >= J.base[i]) j = i;
    const float* W = J.src[j];
    ushort_t* Wt = J.dst[j];
    int K = J.K[j], N = J.N[j];
    int local = tidx - J.base[j];
    int kt = local % (K / 32), nt = local / (K / 32);
    int k0 = kt * 32, n0 = nt * 32;
    int tx = threadIdx.x & 31, ty = threadIdx.x >> 5;   // ty 0..7
#pragma unroll
    for (int i = 0; i < 32; i += 8)
        tile[ty + i][tx] = W[(size_t)(k0 + ty + i) * N + n0 + tx];
    __syncthreads();
#pragma unroll
    for (int i = 0; i < 32; i += 8)
        Wt[(size_t)(n0 + ty + i) * K + k0 + tx] = f2bf(tile[tx][ty + i]);
}

// ---------------------------------------------------------------------------
// MFMA bf16 GEMM (m97 structure): C = A @ Bt^T + bias, bf16 out.
// 128x128 tile, BK=32, 256 threads, 16x16x32 bf16 MFMA.
// ---------------------------------------------------------------------------
__global__ __launch_bounds__(256) void mfma_gemm_kernel(
        const ushort_t* __restrict__ A, const ushort_t* __restrict__ Bt,
        const float* __restrict__ bias, ushort_t* __restrict__ C,
        int M, int N, int K) {
    __shared__ ushort_t As[128 * 32];
    __shared__ ushort_t Bs[128 * 32];
    const int t = threadIdx.x;
    const int m0 = blockIdx.y * 128, n0 = blockIdx.x * 128;
    const int wavebase = (t >> 6) * 64;
    const int lane = t & 63;
    const int lrow = lane & 15, quad = lane >> 4;
    const int m_base = ((t >> 6) >> 1) * 64;
    const int n_base = ((t >> 6) & 1) * 64;
    f32x4 acc[4][4] = {};

    for (int k0 = 0; k0 < K; k0 += 32) {
#pragma unroll
        for (int it = 0; it < 2; ++it) {
            int c = it * 256 + t;
            int row = c >> 2, kc = (c & 3) * 8;
            __builtin_amdgcn_global_load_lds(
                (const __attribute__((address_space(1))) void*)(A + (size_t)(m0 + row) * K + k0 + kc),
                (__attribute__((address_space(3))) void*)(As + (size_t)(it * 256 + wavebase) * 8),
                16, 0, 0);
            __builtin_amdgcn_global_load_lds(
                (const __attribute__((address_space(1))) void*)(Bt + (size_t)(n0 + row) * K + k0 + kc),
                (__attribute__((address_space(3))) void*)(Bs + (size_t)(it * 256 + wavebase) * 8),
                16, 0, 0);
        }
        __syncthreads();
        bf16x8 af[4], bfr[4];
#pragma unroll
        for (int i = 0; i < 4; ++i)
            af[i] = *(const bf16x8*)(As + (m_base + i * 16 + lrow) * 32 + quad * 8);
#pragma unroll
        for (int j = 0; j < 4; ++j)
            bfr[j] = *(const bf16x8*)(Bs + (n_base + j * 16 + lrow) * 32 + quad * 8);
#pragma unroll
        for (int i = 0; i < 4; ++i)
#pragma unroll
            for (int j = 0; j < 4; ++j)
                acc[i][j] = __builtin_amdgcn_mfma_f32_16x16x32_bf16(af[i], bfr[j], acc[i][j], 0, 0, 0);
        __syncthreads();
    }
#pragma unroll
    for (int i = 0; i < 4; ++i) {
#pragma unroll
        for (int j = 0; j < 4; ++j) {
            int n = n0 + n_base + j * 16 + lrow;
            float bv = bias ? bias[n] : 0.f;
#pragma unroll
            for (int r = 0; r < 4; ++r) {
                int m = m0 + m_base + i * 16 + quad * 4 + r;
                C[(size_t)m * N + n] = f2bf(acc[i][j][r] + bv);
            }
        }
    }
}

// ---------------------------------------------------------------------------
// QKV GEMM: A[M,512] bf16 @ Wt[1536,512]^T -> qkv fp16 [M][1536].
// Epilogue also scatters V^T (n in [1024,1536)) into VT[bh][64][320] fp16.
// G = rows per batch item (256 prot / 64 drug); KEYOFF = key offset in concat.
// ---------------------------------------------------------------------------
template<int G, int KEYOFF>
__global__ __launch_bounds__(256) void qkv_gemm_kernel(
        const ushort_t* __restrict__ A, const ushort_t* __restrict__ Bt,
        _Float16* __restrict__ C, _Float16* __restrict__ VT) {
    const int K = 512, N = 1536;
    __shared__ ushort_t As[128 * 32];
    __shared__ ushort_t Bs[128 * 32];
    const int t = threadIdx.x;
    const int m0 = blockIdx.y * 128, n0 = blockIdx.x * 128;
    const int wavebase = (t >> 6) * 64;
    const int lane = t & 63;
    const int lrow = lane & 15, quad = lane >> 4;
    const int m_base = ((t >> 6) >> 1) * 64;
    const int n_base = ((t >> 6) & 1) * 64;
    f32x4 acc[4][4] = {};

    for (int k0 = 0; k0 < K; k0 += 32) {
#pragma unroll
        for (int it = 0; it < 2; ++it) {
            int c = it * 256 + t;
            int row = c >> 2, kc = (c & 3) * 8;
            __builtin_amdgcn_global_load_lds(
                (const __attribute__((address_space(1))) void*)(A + (size_t)(m0 + row) * K + k0 + kc),
                (__attribute__((address_space(3))) void*)(As + (size_t)(it * 256 + wavebase) * 8),
                16, 0, 0);
            __builtin_amdgcn_global_load_lds(
                (const __attribute__((address_space(1))) void*)(Bt + (size_t)(n0 + row) * K + k0 + kc),
                (__attribute__((address_space(3))) void*)(Bs + (size_t)(it * 256 + wavebase) * 8),
                16, 0, 0);
        }
        __syncthreads();
        bf16x8 af[4], bfr[4];
#pragma unroll
        for (int i = 0; i < 4; ++i)
            af[i] = *(const bf16x8*)(As + (m_base + i * 16 + lrow) * 32 + quad * 8);
#pragma unroll
        for (int j = 0; j < 4; ++j)
            bfr[j] = *(const bf16x8*)(Bs + (n_base + j * 16 + lrow) * 32 + quad * 8);
#pragma unroll
        for (int i = 0; i < 4; ++i)
#pragma unroll
            for (int j = 0; j < 4; ++j)
                acc[i][j] = __builtin_amdgcn_mfma_f32_16x16x32_bf16(af[i], bfr[j], acc[i][j], 0, 0, 0);
        __syncthreads();
    }
#pragma unroll
    for (int i = 0; i < 4; ++i) {
#pragma unroll
        for (int j = 0; j < 4; ++j) {
            int n = n0 + n_base + j * 16 + lrow;
            int hh = (n - 1024) >> 6;       // head, valid when n >= 1024
            int dd = n & 63;
#pragma unroll
            for (int r = 0; r < 4; ++r) {
                int m = m0 + m_base + i * 16 + quad * 4 + r;
                _Float16 hv = (_Float16)acc[i][j][r];
                C[(size_t)m * N + n] = hv;
                if (n >= 1024) {
                    int b = m / G, g = m % G;
                    VT[((size_t)(b * 8 + hh) * 64 + dd) * NKEY + KEYOFF + g] = hv;
                }
            }
        }
    }
}

// ---------------------------------------------------------------------------
// Attention logits: per (b,h), S[320,320] = Qcat @ Kcat^T (fp16 out).
// mtile/ntile 0..4: tiles 0-3 = prot rows, 4 = drug rows. K = HD = 64.
// ---------------------------------------------------------------------------
__global__ __launch_bounds__(256) void attn_logits_kernel(
        const _Float16* __restrict__ qkvp, const _Float16* __restrict__ qkvd,
        _Float16* __restrict__ S) {
    __shared__ _Float16 As[64 * 64];
    __shared__ _Float16 Bs[64 * 64];
    const int t = threadIdx.x;
    const int ntile = blockIdx.x, mtile = blockIdx.y, bh = blockIdx.z;
    const int b = bh >> 3, h = bh & 7;
    const _Float16* Abase = (mtile < 4)
        ? qkvp + ((size_t)(b * GP + mtile * 64) * 1536 + h * HD)
        : qkvd + ((size_t)(b * GD) * 1536 + h * HD);
    const _Float16* Bbase = (ntile < 4)
        ? qkvp + ((size_t)(b * GP + ntile * 64) * 1536 + 512 + h * HD)
        : qkvd + ((size_t)(b * GD) * 1536 + 512 + h * HD);
    const int lane = t & 63, wid = t >> 6;
    const int lrow = lane & 15, quad = lane >> 4;
    const int moff = (wid >> 1) * 32, noff = (wid & 1) * 32;

#pragma unroll
    for (int it = 0; it < 2; ++it) {
        int c = it * 256 + t;                 // 512 chunks of 16B (8 f16)
        int row = c >> 3, koff = (c & 7) * 8;
        __builtin_amdgcn_global_load_lds(
            (const __attribute__((address_space(1))) void*)(Abase + (size_t)row * 1536 + koff),
            (__attribute__((address_space(3))) void*)(As + (size_t)(it * 256 + wid * 64) * 8),
            16, 0, 0);
        __builtin_amdgcn_global_load_lds(
            (const __attribute__((address_space(1))) void*)(Bbase + (size_t)row * 1536 + koff),
            (__attribute__((address_space(3))) void*)(Bs + (size_t)(it * 256 + wid * 64) * 8),
            16, 0, 0);
    }
    __syncthreads();

    f32x4 acc[2][2] = {};
#pragma unroll
    for (int ks = 0; ks < 2; ++ks) {
        f16x8 af[2], bfr[2];
#pragma unroll
        for (int i = 0; i < 2; ++i)
            af[i] = *(const f16x8*)(As + (moff + i * 16 + lrow) * 64 + ks * 32 + quad * 8);
#pragma unroll
        for (int j = 0; j < 2; ++j)
            bfr[j] = *(const f16x8*)(Bs + (noff + j * 16 + lrow) * 64 + ks * 32 + quad * 8);
#pragma unroll
        for (int i = 0; i < 2; ++i)
#pragma unroll
            for (int j = 0; j < 2; ++j)
                acc[i][j] = __builtin_amdgcn_mfma_f32_16x16x32_f16(af[i], bfr[j], acc[i][j], 0, 0, 0);
    }
    _Float16* Sb = S + (size_t)bh * NQ * NKEY;
#pragma unroll
    for (int i = 0; i < 2; ++i)
#pragma unroll
        for (int j = 0; j < 2; ++j) {
            int n = ntile * 64 + noff + j * 16 + lrow;
#pragma unroll
            for (int r = 0; r < 4; ++r) {
                int m = mtile * 64 + moff + i * 16 + quad * 4 + r;
                Sb[(size_t)m * NKEY + n] = (_Float16)acc[i][j][r];
            }
        }
}

// ---------------------------------------------------------------------------
// Masked segmented softmax, in place (S fp16 -> P fp16). One wave per row.
// cols 0-255: prot-key softmax; cols 256-319: drug-key softmax.
// Invalid (mrow=0) rows are zeroed (reference's where(mrow, a, 0)).
// ---------------------------------------------------------------------------
__global__ __launch_bounds__(256) void attn_softmax_kernel(
        _Float16* __restrict__ S, const int* __restrict__ mg, const int* __restrict__ md) {
    const int bh = blockIdx.y, b = bh >> 3;
    const int wid = threadIdx.x >> 6, lane = threadIdx.x & 63;
    const int m = blockIdx.x * 4 + wid;   // 0..319
    const int mrow = (m < GP) ? mg[b * GP + m] : md[b * GD + m - GP];
    _Float16* row = S + ((size_t)bh * NQ + m) * NKEY;

    float x[4];
#pragma unroll
    for (int j = 0; j < 4; ++j) {
        int n = lane + j * 64;
        int cm = mg[b * GP + n];
        x[j] = (float)row[n] - ((mrow && cm) ? 0.f : 1e6f);
    }
    int cmd = md[b * GD + lane];
    float xd = (float)row[GP + lane] - ((mrow && cmd) ? 0.f : 1e6f);

    // prot softmax (256)
    float mx = fmaxf(fmaxf(x[0], x[1]), fmaxf(x[2], x[3]));
#pragma unroll
    for (int off = 32; off >= 1; off >>= 1) mx = fmaxf(mx, __shfl_xor(mx, off));
    float e0 = __expf(x[0] - mx), e1 = __expf(x[1] - mx);
    float e2 = __expf(x[2] - mx), e3 = __expf(x[3] - mx);
    float s = e0 + e1 + e2 + e3;
#pragma unroll
    for (int off = 32; off >= 1; off >>= 1) s += __shfl_xor(s, off);
    float sp = mrow ? (1.f / s) : 0.f;
    row[lane] = (_Float16)(e0 * sp);
    row[lane + 64] = (_Float16)(e1 * sp);
    row[lane + 128] = (_Float16)(e2 * sp);
    row[lane + 192] = (_Float16)(e3 * sp);
    // drug softmax (64)
    float mx2 = xd;
#pragma unroll
    for (int off = 32; off >= 1; off >>= 1) mx2 = fmaxf(mx2, __shfl_xor(mx2, off));
    float ed = __expf(xd - mx2);
    float s2 = ed;
#pragma unroll
    for (int off = 32; off >= 1; off >>= 1) s2 += __shfl_xor(s2, off);
    float sd = mrow ? (1.f / s2) : 0.f;
    row[GP + lane] = (_Float16)(ed * sd);
}

// ---------------------------------------------------------------------------
// Mix GEMM: per (b,h), O[320,64] = P[320,320] @ VT[64,320]^T, *0.5,
// scattered to pe[b][g][h*64+d] / de. Row-mask zeroing already in P.
// ---------------------------------------------------------------------------
__global__ __launch_bounds__(256) void attn_mix_kernel(
        const _Float16* __restrict__ P, const _Float16* __restrict__ VT,
        float* __restrict__ pe, float* __restrict__ de) {
    __shared__ _Float16 As[64 * 32];
    __shared__ _Float16 Bs[64 * 32];
    const int t = threadIdx.x;
    const int mtile = blockIdx.x, bh = blockIdx.y;
    const int b = bh >> 3, h = bh & 7;
    const _Float16* Pbase = P + (size_t)bh * NQ * NKEY + (size_t)mtile * 64 * NKEY;
    const _Float16* Vbase = VT + (size_t)bh * HD * NKEY;
    const int lane = t & 63, wid = t >> 6;
    const int lrow = lane & 15, quad = lane >> 4;
    const int moff = (wid >> 1) * 32, noff = (wid & 1) * 32;
    f32x4 acc[2][2] = {};

    for (int k0 = 0; k0 < NKEY; k0 += 32) {
        int row = t >> 2, koff = (t & 3) * 8;    // 256 chunks per matrix
        __builtin_amdgcn_global_load_lds(
            (const __attribute__((address_space(1))) void*)(Pbase + (size_t)row * NKEY + k0 + koff),
            (__attribute__((address_space(3))) void*)(As + (size_t)(wid * 64) * 8),
            16, 0, 0);
        __builtin_amdgcn_global_load_lds(
            (const __attribute__((address_space(1))) void*)(Vbase + (size_t)row * NKEY + k0 + koff),
            (__attribute__((address_space(3))) void*)(Bs + (size_t)(wid * 64) * 8),
            16, 0, 0);
        __syncthreads();
        f16x8 af[2], bfr[2];
#pragma unroll
        for (int i = 0; i < 2; ++i)
            af[i] = *(const f16x8*)(As + (moff + i * 16 + lrow) * 32 + quad * 8);
#pragma unroll
        for (int j = 0; j < 2; ++j)
            bfr[j] = *(const f16x8*)(Bs + (noff + j * 16 + lrow) * 32 + quad * 8);
#pragma unroll
        for (int i = 0; i < 2; ++i)
#pragma unroll
            for (int j = 0; j < 2; ++j)
                acc[i][j] = __builtin_amdgcn_mfma_f32_16x16x32_f16(af[i], bfr[j], acc[i][j], 0, 0, 0);
        __syncthreads();
    }
#pragma unroll
    for (int i = 0; i < 2; ++i)
#pragma unroll
        for (int j = 0; j < 2; ++j) {
            int n = noff + j * 16 + lrow;        // 0..63 = head dim
#pragma unroll
            for (int r = 0; r < 4; ++r) {
                int m = mtile * 64 + moff + i * 16 + quad * 4 + r;
                float v = 0.5f * acc[i][j][r];
                if (m < GP) pe[((size_t)(b * GP + m)) * HID + h * HD + n] = v;
                else        de[((size_t)(b * GD + m - GP)) * HID + h * HD + n] = v;
            }
        }
}

// ---------------------------------------------------------------------------
// Masked-mean pool + concat -> x[B,1024]
// ---------------------------------------------------------------------------
__global__ void pool_kernel(const float* __restrict__ pe, const float* __restrict__ de,
                            const int* __restrict__ mg, const int* __restrict__ md,
                            float* __restrict__ x) {
    const int b = blockIdx.x, d = threadIdx.x;   // 512 threads
    float cnt = 0.f;
    for (int i = 0; i < GP; ++i) cnt += mg[b * GP + i] ? 1.f : 0.f;
    float s = 0.f;
    const float* p = pe + (size_t)b * GP * HID + d;
    for (int i = 0; i < GP; ++i) s += p[(size_t)i * HID];
    x[b * 1024 + d] = s / cnt;
    float cntd = 0.f;
    for (int i = 0; i < GD; ++i) cntd += md[b * GD + i] ? 1.f : 0.f;
    float sd = 0.f;
    const float* pd = de + (size_t)b * GD * HID + d;
    for (int i = 0; i < GD; ++i) sd += pd[(size_t)i * HID];
    x[b * 1024 + 512 + d] = sd / cntd;
}

// ---------------------------------------------------------------------------
// Tiny-M (32) MLP GEMM (fp32), BN, final sigmoid
// ---------------------------------------------------------------------------
__global__ void mlp_gemm_kernel(const float* __restrict__ X, const float* __restrict__ W,
                                const float* __restrict__ bias, float* __restrict__ Y,
                                int K, int N, int do_relu) {
    int g = blockIdx.x * blockDim.x + threadIdx.x;
    int m = g / N, n = g % N;
    float acc = bias[n];
    const float* xr = X + (size_t)m * K;
    const float* wc = W + n;
#pragma unroll 4
    for (int k = 0; k < K; ++k) acc += xr[k] * wc[(size_t)k * N];
    if (do_relu) acc = fmaxf(acc, 0.f);
    Y[g] = acc;
}

__global__ void bn_kernel(float* __restrict__ Y, const float* __restrict__ gamma,
                          const float* __restrict__ beta, int F) {
    int f = blockIdx.x * blockDim.x + threadIdx.x;
    if (f >= F) return;
    float mu = 0.f;
    for (int r = 0; r < BATCH; ++r) mu += Y[(size_t)r * F + f];
    mu *= (1.f / BATCH);
    float var = 0.f;
    for (int r = 0; r < BATCH; ++r) {
        float d = Y[(size_t)r * F + f] - mu;
        var += d * d;
    }
    var *= (1.f / BATCH);
    float sc = gamma[f] * rsqrtf(var + 1e-5f);
    float bb = beta[f];
    for (int r = 0; r < BATCH; ++r)
        Y[(size_t)r * F + f] = (Y[(size_t)r * F + f] - mu) * sc + bb;
}

__global__ void final_kernel(const float* __restrict__ H, const float* __restrict__ wo,
                             const float* __restrict__ bo, float* __restrict__ out) {
    const int b = blockIdx.x, lane = threadIdx.x;   // 64 threads
    float p = 0.f;
#pragma unroll
    for (int j = 0; j < 4; ++j) {
        int idx = lane + j * 64;
        p += H[b * 256 + idx] * wo[idx];
    }
#pragma unroll
    for (int off = 32; off >= 1; off >>= 1) p += __shfl_xor(p, off);
    if (lane == 0) out[b] = 1.f / (1.f + expf(-(p + bo[0])));
}

// ---------------------------------------------------------------------------
extern "C" void kernel_launch(void* const* d_in, const int* in_sizes, int n_in,
                              void* d_out, int out_size, void* d_ws, size_t ws_size,
                              hipStream_t stream) {
    const float* prot_embed = (const float*)d_in[0];
    const float* drug_embed = (const float*)d_in[1];
    const int* prot_mask = (const int*)d_in[2];
    const int* drug_mask = (const int*)d_in[3];
    const float* w_preg = (const float*)d_in[4];
    const float* b_preg = (const float*)d_in[5];
    const float* w_dreg = (const float*)d_in[6];
    const float* b_dreg = (const float*)d_in[7];
    const float* wqp = (const float*)d_in[8];
    const float* wkp = (const float*)d_in[9];
    const float* wvp = (const float*)d_in[10];
    const float* wqd = (const float*)d_in[11];
    const float* wkd = (const float*)d_in[12];
    const float* wvd = (const float*)d_in[13];
    const float* w1 = (const float*)d_in[14];  const float* b1 = (const float*)d_in[15];
    const float* g1 = (const float*)d_in[16];  const float* be1 = (const float*)d_in[17];
    const float* w2 = (const float*)d_in[18];  const float* b2 = (const float*)d_in[19];
    const float* g2 = (const float*)d_in[20];  const float* be2 = (const float*)d_in[21];
    const float* w3 = (const float*)d_in[22];  const float* b3 = (const float*)d_in[23];
    const float* g3 = (const float*)d_in[24];  const float* be3 = (const float*)d_in[25];
    const float* wo = (const float*)d_in[26];  const float* bo = (const float*)d_in[27];

    // ---- workspace layout (elements) ----
    ushort_t* pgm = (ushort_t*)d_ws;                 // [8192][1280] bf16
    ushort_t* dgm = pgm + 10485760;                  // [2048][768] bf16
    ushort_t* wpreg_t = dgm + 1572864;               // [512][1280]
    ushort_t* wdreg_t = wpreg_t + 655360;            // [512][768]
    ushort_t* wqkvp_t = wdreg_t + 393216;            // [1536][512]
    ushort_t* wqkvd_t = wqkvp_t + 786432;            // [1536][512]
    ushort_t* pg = wqkvd_t + 786432;                 // [8192][512] bf16
    ushort_t* dg = pg + 4194304;                     // [2048][512] bf16
    _Float16* qkvp = (_Float16*)(dg + 1048576);      // [8192][1536] f16
    _Float16* qkvd = qkvp + 12582912;                // [2048][1536] f16
    _Float16* VT   = qkvd + 3145728;                 // [256][64][320] f16
    _Float16* S    = VT + 5242880;                   // [256][320][320] f16 (P in place)
    int* mg = (int*)(S + 26214400);                  // [8192]
    int* md = mg + 8192;                             // [2048]
    // overlays: pgm dead after regression GEMM -> pe/de; dgm dead -> MLP tmps
    float* pe = (float*)pgm;                         // [8192][512] f32 (20.97 MB = pgm size)
    float* de = pe + 4194304;                        // [2048][512] f32
    float* x  = (float*)dgm;                         // [32][1024]
    float* h1 = x + 32768;
    float* h2 = h1 + 32768;
    float* h3 = h2 + 16384;

    // 1. group means (mean commutes with the linear regression layers) -> bf16
    group_mean_kernel<<<(BATCH * GP * DP / 4) / 256, 256, 0, stream>>>(prot_embed, pgm, DP / 4, BATCH * GP * DP / 4);
    group_mean_kernel<<<(BATCH * GD * DD / 4) / 256, 256, 0, stream>>>(drug_embed, dgm, DD / 4, BATCH * GD * DD / 4);
    group_mask_kernel<<<(BATCH * GP) / 256, 256, 0, stream>>>(prot_mask, mg, BATCH * GP);
    group_mask_kernel<<<(BATCH * GD) / 256, 256, 0, stream>>>(drug_mask, md, BATCH * GD);

    // 2. all 8 weight transposes in one launch
    TransJobs J;
    J.src[0] = w_preg; J.dst[0] = wpreg_t; J.K[0] = DP;  J.N[0] = HID;
    J.src[1] = w_dreg; J.dst[1] = wdreg_t; J.K[1] = DD;  J.N[1] = HID;
    J.src[2] = wqp; J.dst[2] = wqkvp_t;              J.K[2] = HID; J.N[2] = HID;
    J.src[3] = wkp; J.dst[3] = wqkvp_t + 512 * 512;  J.K[3] = HID; J.N[3] = HID;
    J.src[4] = wvp; J.dst[4] = wqkvp_t + 1024 * 512; J.K[4] = HID; J.N[4] = HID;
    J.src[5] = wqd; J.dst[5] = wqkvd_t;              J.K[5] = HID; J.N[5] = HID;
    J.src[6] = wkd; J.dst[6] = wqkvd_t + 512 * 512;  J.K[6] = HID; J.N[6] = HID;
    J.src[7] = wvd; J.dst[7] = wqkvd_t + 1024 * 512; J.K[7] = HID; J.N[7] = HID;
    {
        int base = 0;
        for (int i = 0; i < 8; ++i) { J.base[i] = base; base += (J.K[i] / 32) * (J.N[i] / 32); }
        transpose_cast8_kernel<<<base, 256, 0, stream>>>(J);
    }

    // 3. regression GEMMs (bf16 out, bias), then fused QKV GEMMs (f16 out + VT)
    mfma_gemm_kernel<<<dim3(HID / 128, (BATCH * GP) / 128), 256, 0, stream>>>(
        pgm, wpreg_t, b_preg, pg, BATCH * GP, HID, DP);
    mfma_gemm_kernel<<<dim3(HID / 128, (BATCH * GD) / 128), 256, 0, stream>>>(
        dgm, wdreg_t, b_dreg, dg, BATCH * GD, HID, DD);
    qkv_gemm_kernel<GP, 0><<<dim3(1536 / 128, (BATCH * GP) / 128), 256, 0, stream>>>(
        pg, wqkvp_t, qkvp, VT);
    qkv_gemm_kernel<GD, GP><<<dim3(1536 / 128, (BATCH * GD) / 128), 256, 0, stream>>>(
        dg, wqkvd_t, qkvd, VT);

    // 4. attention: logits GEMM -> masked segmented softmax (in place) -> mix GEMM
    attn_logits_kernel<<<dim3(5, 5, BATCH * NH), 256, 0, stream>>>(qkvp, qkvd, S);
    attn_softmax_kernel<<<dim3(NQ / 4, BATCH * NH), 256, 0, stream>>>(S, mg, md);
    attn_mix_kernel<<<dim3(5, BATCH * NH), 256, 0, stream>>>(S, VT, pe, de);

    // 5. masked-mean pool + concat
    pool_kernel<<<BATCH, 512, 0, stream>>>(pe, de, mg, md, x);

    // 6. MLP head
    mlp_gemm_kernel<<<(BATCH * 1024) / 256, 256, 0, stream>>>(x, w1, b1, h1, 1024, 1024, 1);
    bn_kernel<<<1024 / 256, 256, 0, stream>>>(h1, g1, be1, 1024);
    mlp_gemm_kernel<<<(BATCH * 512) / 256, 256, 0, stream>>>(h1, w2, b2, h2, 1024, 512, 1);
    bn_kernel<<<512 / 256, 256, 0, stream>>>(h2, g2, be2, 512);
    mlp_gemm_kernel<<<(BATCH * 256) / 256, 256, 0, stream>>>(h2, w3, b3, h3, 512, 256, 1);
    bn_kernel<<<1, 256, 0, stream>>>(h3, g3, be3, 256);
    final_kernel<<<BATCH, 64, 0, stream>>>(h3, wo, bo, (float*)d_out);
}